// Round 1
// baseline (750.130 us; speedup 1.0000x reference)
//
#include <hip/hip_runtime.h>
#include <cstdint>

// Problem constants (fixed by reference)
#define C_   1024
#define IN_  256
#define OUT_ 256
#define B_   256
#define N_   1024

typedef __attribute__((ext_vector_type(8))) short short8;   // 8 bf16 (4 VGPRs)
typedef __attribute__((ext_vector_type(4))) float f32x4;    // MFMA accumulator

// fp32 -> bf16, round-to-nearest-even (bit trick; inputs are finite)
__device__ __forceinline__ uint16_t f2bf(float f) {
    uint32_t u = __builtin_bit_cast(uint32_t, f);
    return (uint16_t)((u + 0x7FFFu + ((u >> 16) & 1u)) >> 16);
}

// ---------------------------------------------------------------------------
// Kernel 1: gather + transpose + convert  weight[idx[b]] (fp32 [IN][OUT])
//           -> WT[b][o][k] (bf16, k-contiguous) in d_ws.
// grid (8, B_): blockIdx.x = 32-wide o-strip, blockIdx.y = batch. 256 thr.
// ---------------------------------------------------------------------------
__global__ __launch_bounds__(256) void prep_wt(
    const float* __restrict__ weight, const int* __restrict__ idx,
    uint16_t* __restrict__ wt) {
    __shared__ float tile[IN_][33];   // [k][o_local], pad 33 -> conflict-free
    const int b  = blockIdx.y;
    const int o0 = blockIdx.x * 32;
    const int ci = idx[b];
    const float* wsrc = weight + (size_t)ci * (IN_ * OUT_);
    const int t = threadIdx.x;

    // Load 256 k-rows x 32 o-cols, coalesced along o.
    const int o_l   = t & 31;
    const int kbase = t >> 5;           // 0..7
    #pragma unroll
    for (int rep = 0; rep < 32; ++rep) {
        int k = rep * 8 + kbase;
        tile[k][o_l] = wsrc[k * OUT_ + o0 + o_l];
    }
    __syncthreads();

    // Write transposed: wt[b][o][k], 2 k-values per thread (packed u32),
    // coalesced along k.
    const int k2   = (t & 127) * 2;
    const int osel = t >> 7;            // 0..1
    uint32_t* dst = (uint32_t*)(wt + (size_t)b * (IN_ * OUT_));
    #pragma unroll
    for (int rep = 0; rep < 16; ++rep) {
        int o = rep * 2 + osel;
        uint32_t lo = f2bf(tile[k2][o]);
        uint32_t hi = f2bf(tile[k2 + 1][o]);
        dst[((o0 + o) * IN_ + k2) >> 1] = lo | (hi << 16);
    }
}

// ---------------------------------------------------------------------------
// Kernel 2: per-batch GEMM  out[b] = x[b] @ W_b + bias_b
// Tile: BM=64 (n-rows) x BN=256 (all OUT) x BK=32. 256 threads = 4 waves,
// wave w owns o-columns [w*64, w*64+64): 4x4 grid of 16x16x32 bf16 MFMAs.
// x fp32 converted to bf16 inline during LDS staging; W read from WT (bf16).
// grid (N_/64, B_).
// ---------------------------------------------------------------------------
#define BM 64
#define BK 32
#define LDA 40   // LDS row stride in bf16 elems (32 + 8 pad, keeps 16B align)

__global__ __launch_bounds__(256) void gemm_bn256(
    const float* __restrict__ x, const int* __restrict__ idx,
    const uint16_t* __restrict__ wt, const float* __restrict__ bias,
    float* __restrict__ out) {
    __shared__ __align__(16) uint16_t As[BM * LDA];     // 64 x 40 bf16
    __shared__ __align__(16) uint16_t Ws[OUT_ * LDA];   // 256 x 40 bf16

    const int b  = blockIdx.y;
    const int n0 = blockIdx.x * BM;
    const int ci = idx[b];
    const int t    = threadIdx.x;
    const int lane = t & 63;
    const int w    = t >> 6;            // wave id = o-quarter

    const float*    xsrc = x  + (size_t)b * (N_ * IN_) + (size_t)n0 * IN_;
    const uint16_t* wsrc = wt + (size_t)b * (IN_ * OUT_);

    // Staging assignments
    const int arow = t >> 2, aq = t & 3;    // A: 64 rows x 4 quarters (8 f32 each)
    const int wrow = t >> 2, wq = t & 3;    // W: 4 reps x 64 rows x 4 segs (8 bf16)

    f32x4 acc[4][4] = {};

    float4 ra[2];
    uint4  rw[4];

    auto loadA = [&](int k0) {
        const float* p = xsrc + arow * IN_ + k0 + aq * 8;
        ra[0] = *(const float4*)(p);
        ra[1] = *(const float4*)(p + 4);
    };
    auto loadW = [&](int k0) {
        #pragma unroll
        for (int r = 0; r < 4; ++r) {
            const uint16_t* p = wsrc + (size_t)(r * 64 + wrow) * IN_ + k0 + wq * 8;
            rw[r] = *(const uint4*)(p);
        }
    };
    auto storeLDS = [&]() {
        float af[8] = {ra[0].x, ra[0].y, ra[0].z, ra[0].w,
                       ra[1].x, ra[1].y, ra[1].z, ra[1].w};
        union { uint16_t u16[8]; uint4 v; } pk;
        #pragma unroll
        for (int i = 0; i < 8; ++i) pk.u16[i] = f2bf(af[i]);
        *(uint4*)&As[arow * LDA + aq * 8] = pk.v;
        #pragma unroll
        for (int r = 0; r < 4; ++r)
            *(uint4*)&Ws[(r * 64 + wrow) * LDA + wq * 8] = rw[r];
    };

    const int m = lane & 15, g = lane >> 4;

    loadA(0);
    loadW(0);
    #pragma unroll
    for (int kt = 0; kt < IN_ / BK; ++kt) {
        __syncthreads();
        storeLDS();
        __syncthreads();
        if (kt < IN_ / BK - 1) { loadA((kt + 1) * BK); loadW((kt + 1) * BK); }

        short8 a[4], bb[4];
        #pragma unroll
        for (int mi = 0; mi < 4; ++mi)
            a[mi] = *(const short8*)&As[(mi * 16 + m) * LDA + g * 8];
        #pragma unroll
        for (int ni = 0; ni < 4; ++ni)
            bb[ni] = *(const short8*)&Ws[(w * 64 + ni * 16 + m) * LDA + g * 8];
        #pragma unroll
        for (int mi = 0; mi < 4; ++mi)
            #pragma unroll
            for (int ni = 0; ni < 4; ++ni)
                acc[mi][ni] = __builtin_amdgcn_mfma_f32_16x16x32_bf16(
                    a[mi], bb[ni], acc[mi][ni], 0, 0, 0);
    }

    // Epilogue: C/D layout col = lane&15, row = (lane>>4)*4 + reg
    float bv[4];
    const float* bsrc = bias + (size_t)ci * OUT_;
    #pragma unroll
    for (int ni = 0; ni < 4; ++ni) bv[ni] = bsrc[w * 64 + ni * 16 + m];

    float* odst = out + (size_t)b * (N_ * OUT_) + (size_t)n0 * OUT_;
    #pragma unroll
    for (int mi = 0; mi < 4; ++mi)
        #pragma unroll
        for (int ni = 0; ni < 4; ++ni)
            #pragma unroll
            for (int v = 0; v < 4; ++v) {
                int row = mi * 16 + g * 4 + v;
                int col = w * 64 + ni * 16 + m;
                odst[row * OUT_ + col] = acc[mi][ni][v] + bv[ni];
            }
}

// ---------------------------------------------------------------------------
extern "C" void kernel_launch(void* const* d_in, const int* in_sizes, int n_in,
                              void* d_out, int out_size, void* d_ws, size_t ws_size,
                              hipStream_t stream) {
    const float* x      = (const float*)d_in[0];
    const int*   idx    = (const int*)d_in[1];
    const float* weight = (const float*)d_in[2];
    const float* bias   = (const float*)d_in[3];
    float*       out    = (float*)d_out;
    uint16_t*    wt     = (uint16_t*)d_ws;   // B_*IN_*OUT_ bf16 = 33.5 MB

    prep_wt<<<dim3(8, B_), 256, 0, stream>>>(weight, idx, wt);
    gemm_bn256<<<dim3(N_ / BM, B_), 256, 0, stream>>>(x, idx, wt, bias, out);
}

// Round 2
// 593.427 us; speedup vs baseline: 1.2641x; 1.2641x over previous
//
#include <hip/hip_runtime.h>
#include <cstdint>

// Problem constants (fixed by reference)
#define C_   1024
#define IN_  256
#define OUT_ 256
#define B_   256
#define N_   1024

#define BM 128
#define BK 32
#define NTHREADS 512

typedef __attribute__((ext_vector_type(8))) short short8;   // 8 bf16 (4 VGPRs)
typedef __attribute__((ext_vector_type(4))) float f32x4;    // MFMA accumulator

// fp32 -> bf16, round-to-nearest-even
__device__ __forceinline__ uint16_t f2bf(float f) {
    uint32_t u = __builtin_bit_cast(uint32_t, f);
    return (uint16_t)((u + 0x7FFFu + ((u >> 16) & 1u)) >> 16);
}

// async global->LDS, 16B per lane. lds dest must be wave-uniform base;
// HW writes lane l's 16B at base + l*16.
__device__ __forceinline__ void glds16(const void* g, void* l) {
    __builtin_amdgcn_global_load_lds(
        (const __attribute__((address_space(1))) void*)g,
        (__attribute__((address_space(3))) void*)l,
        16, 0, 0);
}

// ---------------------------------------------------------------------------
// Kernel 1: gather + transpose + convert  weight[idx[b]] (fp32 [IN][OUT])
//           -> WT[b][o][k] (bf16, k-contiguous) in d_ws.
// grid (8, B_): blockIdx.x = 32-wide o-strip, blockIdx.y = batch. 256 thr.
// ---------------------------------------------------------------------------
__global__ __launch_bounds__(256) void prep_wt(
    const float* __restrict__ weight, const int* __restrict__ idx,
    uint16_t* __restrict__ wt) {
    __shared__ float tile[IN_][33];   // [k][o_local], pad 33 -> conflict-free
    const int b  = blockIdx.y;
    const int o0 = blockIdx.x * 32;
    const int ci = idx[b];
    const float* wsrc = weight + (size_t)ci * (IN_ * OUT_);
    const int t = threadIdx.x;

    // Load 256 k-rows x 32 o-cols, coalesced along o.
    const int o_l   = t & 31;
    const int kbase = t >> 5;           // 0..7
    #pragma unroll
    for (int rep = 0; rep < 32; ++rep) {
        int k = rep * 8 + kbase;
        tile[k][o_l] = wsrc[k * OUT_ + o0 + o_l];
    }
    __syncthreads();

    // Write transposed: wt[b][o][k], 2 k-values per thread (packed u32),
    // coalesced along k.
    const int k2   = (t & 127) * 2;
    const int osel = t >> 7;            // 0..1
    uint32_t* dst = (uint32_t*)(wt + (size_t)b * (IN_ * OUT_));
    #pragma unroll
    for (int rep = 0; rep < 16; ++rep) {
        int o = rep * 2 + osel;
        uint32_t lo = f2bf(tile[k2][o]);
        uint32_t hi = f2bf(tile[k2 + 1][o]);
        dst[((o0 + o) * IN_ + k2) >> 1] = lo | (hi << 16);
    }
}

// ---------------------------------------------------------------------------
// Kernel 2: per-batch GEMM  out[b] = x[b] @ W_b + bias_b
// BM=128 (n) x BN=256 (all OUT) x BK=32. 512 threads = 8 waves in a 2(m)x4(n)
// grid; each wave owns a 64x64 patch = 4x4 mfma_f32_16x16x32_bf16.
// W tile staged via global_load_lds (16B/lane); x converted fp32->bf16 in
// registers. Epilogue stages C through LDS for full-line float4 stores.
// grid (N_/BM = 8, B_).
// ---------------------------------------------------------------------------
__global__ __launch_bounds__(NTHREADS, 2) void gemm_bn256(
    const float* __restrict__ x, const int* __restrict__ idx,
    const uint16_t* __restrict__ wt, const float* __restrict__ bias,
    float* __restrict__ out) {
    __shared__ __align__(16) uint8_t smem[32768];
    uint16_t* As = (uint16_t*)smem;            // [128][32] bf16, 8 KB
    uint16_t* Ws = (uint16_t*)(smem + 8192);   // [256][32] bf16, 16 KB
    float*    Ep = (float*)smem;               // [32][256] fp32, 32 KB (epilogue)

    const int b    = blockIdx.y;
    const int n0   = blockIdx.x * BM;
    const int t    = threadIdx.x;
    const int lane = t & 63;
    const int wv   = t >> 6;            // wave id 0..7
    const int wm   = wv >> 2;           // m-half 0..1
    const int wn   = wv & 3;            // n-quarter 0..3
    const int m    = lane & 15;
    const int g    = lane >> 4;

    const float*    xsrc = x  + (size_t)b * (N_ * IN_) + (size_t)n0 * IN_;
    const uint16_t* wsrc = wt + (size_t)b * (IN_ * OUT_);

    // A staging: thread -> row t>>2 (0..127), quarter q = t&3 (8 floats)
    const int arow = t >> 2, aq = t & 3;
    const float* aptr = xsrc + arow * IN_ + aq * 8;

    float4 ra0, ra1;
    auto loadA = [&](int k0) {
        ra0 = *(const float4*)(aptr + k0);
        ra1 = *(const float4*)(aptr + k0 + 4);
    };

    f32x4 acc[4][4] = {};

    loadA(0);
    #pragma unroll
    for (int kt = 0; kt < IN_ / BK; ++kt) {
        const int k0 = kt * BK;
        __syncthreads();   // prior readers of As/Ws done

        // stage A: convert 8 fp32 -> 8 bf16, one b128 LDS write
        {
            float af[8] = {ra0.x, ra0.y, ra0.z, ra0.w,
                           ra1.x, ra1.y, ra1.z, ra1.w};
            union { uint16_t u[8]; uint4 v; } pk;
            #pragma unroll
            for (int i = 0; i < 8; ++i) pk.u[i] = f2bf(af[i]);
            *(uint4*)&As[arow * BK + aq * 8] = pk.v;
        }
        // stage W: 2 glds rounds; round j covers o-rows [j*128, j*128+128)
        #pragma unroll
        for (int j = 0; j < 2; ++j) {
            const uint16_t* gp = wsrc + (size_t)(j * 128 + (t >> 2)) * IN_
                                 + k0 + (t & 3) * 8;
            void* lp = (uint8_t*)Ws + j * 8192 + wv * 1024;  // wave-uniform
            glds16(gp, lp);
        }
        __syncthreads();   // drains vmcnt (glds) + lgkm (ds_write)

        if (kt < IN_ / BK - 1) loadA(k0 + BK);   // prefetch next A

        short8 a[4], bb[4];
        #pragma unroll
        for (int mi = 0; mi < 4; ++mi)
            a[mi] = *(const short8*)&As[(wm * 64 + mi * 16 + m) * BK + g * 8];
        #pragma unroll
        for (int ni = 0; ni < 4; ++ni)
            bb[ni] = *(const short8*)&Ws[(wn * 64 + ni * 16 + m) * BK + g * 8];
        #pragma unroll
        for (int mi = 0; mi < 4; ++mi)
            #pragma unroll
            for (int ni = 0; ni < 4; ++ni)
                acc[mi][ni] = __builtin_amdgcn_mfma_f32_16x16x32_bf16(
                    a[mi], bb[ni], acc[mi][ni], 0, 0, 0);
    }

    // Epilogue: per mi-chunk (32 rows x 256 cols fp32 = 32 KB), stage through
    // LDS then write full-line float4 runs.
    const int ci = idx[b];
    float bv[4];
    #pragma unroll
    for (int ni = 0; ni < 4; ++ni)
        bv[ni] = bias[(size_t)ci * OUT_ + wn * 64 + ni * 16 + m];

    float* odst = out + (size_t)b * (N_ * OUT_) + (size_t)n0 * OUT_;
    const int rd_row = t >> 4;     // 0..31
    const int c4b    = t & 15;
    #pragma unroll
    for (int mi = 0; mi < 4; ++mi) {
        __syncthreads();   // previous users of smem done
        #pragma unroll
        for (int ni = 0; ni < 4; ++ni)
            #pragma unroll
            for (int v = 0; v < 4; ++v)
                Ep[(wm * 16 + g * 4 + v) * OUT_ + wn * 64 + ni * 16 + m] =
                    acc[mi][ni][v] + bv[ni];
        __syncthreads();
        const int orow = (rd_row >> 4) * 64 + mi * 16 + (rd_row & 15);
        const float4* ep4 = (const float4*)Ep;
        float4* o4 = (float4*)(odst + orow * OUT_);
        #pragma unroll
        for (int rep = 0; rep < 4; ++rep) {
            int c4 = rep * 16 + c4b;
            o4[c4] = ep4[rd_row * 64 + c4];
        }
    }
}

// ---------------------------------------------------------------------------
extern "C" void kernel_launch(void* const* d_in, const int* in_sizes, int n_in,
                              void* d_out, int out_size, void* d_ws, size_t ws_size,
                              hipStream_t stream) {
    const float* x      = (const float*)d_in[0];
    const int*   idx    = (const int*)d_in[1];
    const float* weight = (const float*)d_in[2];
    const float* bias   = (const float*)d_in[3];
    float*       out    = (float*)d_out;
    uint16_t*    wt     = (uint16_t*)d_ws;   // B_*IN_*OUT_ bf16 = 33.5 MB

    prep_wt<<<dim3(8, B_), 256, 0, stream>>>(weight, idx, wt);
    gemm_bn256<<<dim3(N_ / BM, B_), NTHREADS, 0, stream>>>(x, idx, wt, bias, out);
}